// Round 4
// baseline (409.707 us; speedup 1.0000x reference)
//
#include <hip/hip_runtime.h>

#define NN 50000
#define EE 800000
#define NEG 0.2f
#define CAP 128   // per-wave LDS edge stash (deg ~Poisson(16), max ~45; tail path kept for safety)

typedef long long i64;
typedef unsigned int u32;
typedef unsigned short u16;

static __device__ __forceinline__ float wave_max64(float v) {
#pragma unroll
  for (int m = 32; m >= 1; m >>= 1) v = fmaxf(v, __shfl_xor(v, m, 64));
  return v;
}
static __device__ __forceinline__ float wave_sum64(float v) {
#pragma unroll
  for (int m = 32; m >= 1; m >>= 1) v += __shfl_xor(v, m, 64);
  return v;
}

// bf16 helpers
static __device__ __forceinline__ u16 f2bf(float f) {
  u32 u = __float_as_uint(f);
  u += 0x7FFFu + ((u >> 16) & 1u);
  return (u16)(u >> 16);
}
static __device__ __forceinline__ float bf2f(u16 b) {
  return __uint_as_float(((u32)b) << 16);
}
// dword holding two bf16: lo = features[2k], hi = features[2k+1]
static __device__ __forceinline__ float bflo(u32 v) { return __uint_as_float(v << 16); }
static __device__ __forceinline__ float bfhi(u32 v) { return __uint_as_float(v & 0xffff0000u); }

// ---- edge_index dtype probe ----------------------------------------------
__global__ void k_detect(const void* ei, int* flag) {
  __shared__ int sbad[4];
  int t = threadIdx.x;
  const i64* p = (const i64*)ei;
  i64 v = p[t];
  int bad = (v < 0 || v >= NN) ? 1 : 0;
  unsigned long long b = __ballot(bad);
  if ((t & 63) == 0) sbad[t >> 6] = (b != 0ULL);
  __syncthreads();
  if (t == 0) *flag = !(sbad[0] | sbad[1] | sbad[2] | sbad[3]);
}

static __device__ __forceinline__ int edge_at(const void* ei, int is64, int idx) {
  return is64 ? (int)((const i64*)ei)[idx] : ((const int*)ei)[idx];
}

// ---- CSR build (by destination) ------------------------------------------
__global__ void k_zero(int* deg, int* cur) {
  int i = blockIdx.x * blockDim.x + threadIdx.x;
  if (i < NN) { deg[i] = 0; cur[i] = 0; }
}

__global__ void k_count(const void* ei, const int* flag, int* deg) {
  int e = blockIdx.x * blockDim.x + threadIdx.x;
  if (e >= EE) return;
  int is64 = *flag;
  atomicAdd(&deg[edge_at(ei, is64, EE + e)], 1);
}

__global__ void k_dinv(const int* deg, float* dinv) {
  int i = blockIdx.x * blockDim.x + threadIdx.x;
  if (i < NN) dinv[i] = rsqrtf((float)(deg[i] + 1));
}

__global__ void k_scan1(const int* deg, int* rowp, int* bsums) {
  __shared__ int sh[256];
  int t = threadIdx.x;
  int base = blockIdx.x * 1024 + t * 4;
  int v[4]; int s = 0;
#pragma unroll
  for (int j = 0; j < 4; ++j) { int idx = base + j; int x = (idx < NN) ? deg[idx] : 0; v[j] = x; s += x; }
  sh[t] = s; __syncthreads();
  for (int off = 1; off < 256; off <<= 1) {
    int x = (t >= off) ? sh[t - off] : 0;
    __syncthreads();
    sh[t] += x;
    __syncthreads();
  }
  if (t == 255) bsums[blockIdx.x] = sh[255];
  int run = sh[t] - s;
#pragma unroll
  for (int j = 0; j < 4; ++j) { int idx = base + j; if (idx < NN) rowp[idx] = run; run += v[j]; }
}

__global__ void k_scan2(int* bsums, int* rowp, int nb) {
  int lane = threadIdx.x & 63;
  int v = (lane < nb) ? bsums[lane] : 0;
  int x = v;
#pragma unroll
  for (int off = 1; off < 64; off <<= 1) {
    int y = __shfl_up(x, off, 64);
    if (lane >= off) x += y;
  }
  if (lane < nb) bsums[lane] = x - v;
  if (lane == 63) rowp[NN] = x;
}

__global__ void k_scan3(int* rowp, const int* bsums) {
  int i = blockIdx.x * blockDim.x + threadIdx.x;
  if (i < NN) rowp[i] += bsums[i >> 10];
}

__global__ void k_fill(const void* ei, const int* flag, const int* rowp, int* cur, int* csr) {
  int e = blockIdx.x * blockDim.x + threadIdx.x;
  if (e >= EE) return;
  int is64 = *flag;
  int s = edge_at(ei, is64, e);
  int d = edge_at(ei, is64, EE + e);
  int pos = rowp[d] + atomicAdd(&cur[d], 1);
  csr[pos] = s;
}

// ---- dense GEMM: Y(bf16)[n][OC] = X(f32)[n][K] @ W[K][OC] ----------------
template <int K, int OC, int ROWS>
__global__ void k_gemm(const float* __restrict__ X, const float* __restrict__ W,
                       u16* __restrict__ Y, int n) {
  __shared__ __align__(16) float Wl[K * OC];
  int t = threadIdx.x;
  for (int i = t; i < K * OC / 4; i += 256)
    ((float4*)Wl)[i] = ((const float4*)W)[i];
  __syncthreads();

  const int CP = OC / 2;
  const int RP = 256 / CP;
  int tx = t % CP, ty = t / CP;
  int blockRow = blockIdx.x * ROWS;
  const float2* Wl2 = (const float2*)Wl;

  for (int rp = 0; rp < ROWS; rp += RP * 2) {
    int r0 = blockRow + rp + ty * 2;
    if (r0 >= n) break;
    int r1 = r0 + 1;
    bool has1 = (r1 < n);
    const float4* x0q = (const float4*)(X + (size_t)r0 * K);
    const float4* x1q = (const float4*)(X + (size_t)(has1 ? r1 : r0) * K);
    float a00 = 0.f, a01 = 0.f, a10 = 0.f, a11 = 0.f;
#pragma unroll 4
    for (int k4 = 0; k4 < K / 4; ++k4) {
      float4 xa = x0q[k4];
      float4 xb = x1q[k4];
      const float* pa = &xa.x;
      const float* pb = &xb.x;
#pragma unroll
      for (int j = 0; j < 4; ++j) {
        float2 w2 = Wl2[(k4 * 4 + j) * CP + tx];
        a00 += pa[j] * w2.x; a01 += pa[j] * w2.y;
        a10 += pb[j] * w2.x; a11 += pb[j] * w2.y;
      }
    }
    ((ushort2*)(Y + (size_t)r0 * OC))[tx] = make_ushort2(f2bf(a00), f2bf(a01));
    if (has1) ((ushort2*)(Y + (size_t)r1 * OC))[tx] = make_ushort2(f2bf(a10), f2bf(a11));
  }
}

// ---- GCN aggregation: wave/node; halves process alternate edges ----------
// Each lane gathers one dword (2 bf16 features); fp = lane&31 covers features 2fp,2fp+1.
__global__ void k_gcn(const u16* __restrict__ g, const float* __restrict__ dinv,
                      const int* __restrict__ rowp, const int* __restrict__ csr,
                      const float* __restrict__ bias, float* __restrict__ out) {
  __shared__ float2 st[4][CAP];
  int wid = (blockIdx.x * blockDim.x + threadIdx.x) >> 6;
  int w = (threadIdx.x >> 6) & 3;
  int lane = threadIdx.x & 63;
  if (wid >= NN) return;
  float di = dinv[wid];
  int beg = rowp[wid], cnt = rowp[wid + 1] - beg;
  int c1 = min(cnt, CAP);

  for (int idx = lane; idx < c1; idx += 64) {
    int s = csr[beg + idx];
    st[w][idx] = make_float2(__int_as_float(s), dinv[s]);
  }

  int half = lane >> 5, fp = lane & 31;
  const u32* g2 = (const u32*)g;   // 32 dwords per node row
  float acc0 = 0.f, acc1 = 0.f;
  for (int idx = half; idx < c1; idx += 2) {
    float2 p = st[w][idx];
    int s = __float_as_int(p.x);
    u32 v = g2[(size_t)s * 32 + fp];
    acc0 += bflo(v) * p.y;
    acc1 += bfhi(v) * p.y;
  }
  for (int idx = CAP + half; idx < cnt; idx += 2) {  // essentially never
    int s = csr[beg + idx];
    float ws = dinv[s];
    u32 v = g2[(size_t)s * 32 + fp];
    acc0 += bflo(v) * ws;
    acc1 += bfhi(v) * ws;
  }
  if (half == 0) {  // self loop
    u32 v = g2[(size_t)wid * 32 + fp];
    acc0 += bflo(v) * di;
    acc1 += bfhi(v) * di;
  }
  acc0 += __shfl_xor(acc0, 32, 64);
  acc1 += __shfl_xor(acc1, 32, 64);
  if (half == 0) {
    float v0 = fmaxf(acc0 * di + bias[2 * fp], 0.f);
    float v1 = fmaxf(acc1 * di + bias[2 * fp + 1], 0.f);
    ((float2*)(out + (size_t)wid * 64))[fp] = make_float2(v0, v1);
  }
}

// ---- attention coefficients (bf16 h) -------------------------------------
__global__ void k_att1(const u16* __restrict__ hg, const float* __restrict__ aw_s,
                       const float* __restrict__ aw_d, float* __restrict__ a_s,
                       float* __restrict__ a_d) {
  int wid = (blockIdx.x * blockDim.x + threadIdx.x) >> 6;
  int lane = threadIdx.x & 63;
  if (wid >= NN) return;
  const u16* h = hg + (size_t)wid * 128;
  float h0 = bf2f(h[lane]), h1 = bf2f(h[lane + 64]);
  float s0 = wave_sum64(h0 * aw_s[lane]);
  float s1 = wave_sum64(h1 * aw_s[lane + 64]);
  float d0 = wave_sum64(h0 * aw_d[lane]);
  float d1 = wave_sum64(h1 * aw_d[lane + 64]);
  if (lane == 0) {
    a_s[wid * 2] = s0; a_s[wid * 2 + 1] = s1;
    a_d[wid * 2] = d0; a_d[wid * 2 + 1] = d1;
  }
}

__global__ void k_att2(const u16* __restrict__ hg, const float* __restrict__ aw_s,
                       const float* __restrict__ aw_d, float* __restrict__ a_s,
                       float* __restrict__ a_d) {
  int wid = (blockIdx.x * blockDim.x + threadIdx.x) >> 6;
  int lane = threadIdx.x & 63;
  if (wid >= NN) return;
  float h0 = bf2f(hg[(size_t)wid * 64 + lane]);
  float s = h0 * aw_s[lane];
  float d = h0 * aw_d[lane];
#pragma unroll
  for (int m = 16; m >= 1; m >>= 1) { s += __shfl_xor(s, m, 64); d += __shfl_xor(d, m, 64); }
  if ((lane & 31) == 0) {
    a_s[wid * 2 + (lane >> 5)] = s;
    a_d[wid * 2 + (lane >> 5)] = d;
  }
}

// ---- GAT layer 1: wave per node, BOTH heads; lane = dword of 128-f row ---
__global__ void k_gat1(const u16* __restrict__ hg, const float* __restrict__ a_s,
                       const float* __restrict__ a_d, const int* __restrict__ rowp,
                       const int* __restrict__ csr, const float* __restrict__ bias,
                       float* __restrict__ out) {
  __shared__ float4 st[4][CAP];  // (src bits, e0/ex0, e1/ex1, pad)
  int wid = (blockIdx.x * blockDim.x + threadIdx.x) >> 6;
  int w = (threadIdx.x >> 6) & 3;
  int lane = threadIdx.x & 63;
  if (wid >= NN) return;
  int beg = rowp[wid], cnt = rowp[wid + 1] - beg;
  int tot = cnt + 1;
  int c1 = min(tot, CAP);
  float ad0 = a_d[wid * 2], ad1 = a_d[wid * 2 + 1];

  // phase 1: stash (src, e0, e1), maxes
  float m0 = -1e30f, m1 = -1e30f;
  for (int idx = lane; idx < c1; idx += 64) {
    int s = (idx < cnt) ? csr[beg + idx] : wid;
    float e0 = a_s[s * 2] + ad0, e1 = a_s[s * 2 + 1] + ad1;
    e0 = e0 > 0.f ? e0 : NEG * e0;
    e1 = e1 > 0.f ? e1 : NEG * e1;
    st[w][idx] = make_float4(__int_as_float(s), e0, e1, 0.f);
    m0 = fmaxf(m0, e0); m1 = fmaxf(m1, e1);
  }
  for (int idx = CAP + lane; idx < tot; idx += 64) {
    int s = (idx < cnt) ? csr[beg + idx] : wid;
    float e0 = a_s[s * 2] + ad0, e1 = a_s[s * 2 + 1] + ad1;
    e0 = e0 > 0.f ? e0 : NEG * e0;
    e1 = e1 > 0.f ? e1 : NEG * e1;
    m0 = fmaxf(m0, e0); m1 = fmaxf(m1, e1);
  }
  m0 = wave_max64(m0); m1 = wave_max64(m1);

  // phase 2: exp + sums
  float s0 = 0.f, s1 = 0.f;
  for (int idx = lane; idx < c1; idx += 64) {
    float4 p = st[w][idx];
    float x0 = __expf(p.y - m0), x1 = __expf(p.z - m1);
    st[w][idx] = make_float4(p.x, x0, x1, 0.f);
    s0 += x0; s1 += x1;
  }
  for (int idx = CAP + lane; idx < tot; idx += 64) {
    int s = (idx < cnt) ? csr[beg + idx] : wid;
    float e0 = a_s[s * 2] + ad0, e1 = a_s[s * 2 + 1] + ad1;
    e0 = e0 > 0.f ? e0 : NEG * e0;
    e1 = e1 > 0.f ? e1 : NEG * e1;
    s0 += __expf(e0 - m0); s1 += __expf(e1 - m1);
  }
  s0 = wave_sum64(s0); s1 = wave_sum64(s1);
  bool hi = (lane >= 32);                  // lane's head
  float invh = 1.f / (hi ? s1 : s0);

  // phase 3: all 64 lanes per edge; lane reads dword `lane` of the row
  const u32* hg2 = (const u32*)hg;  // 64 dwords per node row
  float acc0 = 0.f, acc1 = 0.f;
#pragma unroll 4
  for (int idx = 0; idx < c1; ++idx) {
    float4 p = st[w][idx];
    int s = __float_as_int(p.x);
    float a = hi ? p.z : p.y;
    u32 v = hg2[(size_t)s * 64 + lane];
    acc0 += bflo(v) * a;
    acc1 += bfhi(v) * a;
  }
  for (int idx = CAP; idx < tot; ++idx) {
    int s = (idx < cnt) ? csr[beg + idx] : wid;
    float e = hi ? (a_s[s * 2 + 1] + ad1) : (a_s[s * 2] + ad0);
    e = e > 0.f ? e : NEG * e;
    float a = __expf(e - (hi ? m1 : m0));
    u32 v = hg2[(size_t)s * 64 + lane];
    acc0 += bflo(v) * a;
    acc1 += bfhi(v) * a;
  }
  float v0 = fmaxf(acc0 * invh + bias[2 * lane], 0.f);
  float v1 = fmaxf(acc1 * invh + bias[2 * lane + 1], 0.f);
  ((float2*)(out + (size_t)wid * 128))[lane] = make_float2(v0, v1);
}

// ---- GAT layer 2 (H=2,C=32, head-mean) + log_softmax ---------------------
// halves process alternate edges; lane's dword fp covers head fp>>4, channels 2*(fp&15)..+1
__global__ void k_gat2(const u16* __restrict__ hg, const float* __restrict__ a_s,
                       const float* __restrict__ a_d, const int* __restrict__ rowp,
                       const int* __restrict__ csr, const float* __restrict__ bias,
                       float* __restrict__ out) {
  __shared__ float4 st[4][CAP];
  int wid = (blockIdx.x * blockDim.x + threadIdx.x) >> 6;
  int w = (threadIdx.x >> 6) & 3;
  int lane = threadIdx.x & 63;
  if (wid >= NN) return;
  int beg = rowp[wid], cnt = rowp[wid + 1] - beg;
  int tot = cnt + 1;
  int c1 = min(tot, CAP);
  float ad0 = a_d[wid * 2], ad1 = a_d[wid * 2 + 1];

  float m0 = -1e30f, m1 = -1e30f;
  for (int idx = lane; idx < c1; idx += 64) {
    int s = (idx < cnt) ? csr[beg + idx] : wid;
    float e0 = a_s[s * 2] + ad0, e1 = a_s[s * 2 + 1] + ad1;
    e0 = e0 > 0.f ? e0 : NEG * e0;
    e1 = e1 > 0.f ? e1 : NEG * e1;
    st[w][idx] = make_float4(__int_as_float(s), e0, e1, 0.f);
    m0 = fmaxf(m0, e0); m1 = fmaxf(m1, e1);
  }
  for (int idx = CAP + lane; idx < tot; idx += 64) {
    int s = (idx < cnt) ? csr[beg + idx] : wid;
    float e0 = a_s[s * 2] + ad0, e1 = a_s[s * 2 + 1] + ad1;
    e0 = e0 > 0.f ? e0 : NEG * e0;
    e1 = e1 > 0.f ? e1 : NEG * e1;
    m0 = fmaxf(m0, e0); m1 = fmaxf(m1, e1);
  }
  m0 = wave_max64(m0); m1 = wave_max64(m1);

  float s0 = 0.f, s1 = 0.f;
  for (int idx = lane; idx < c1; idx += 64) {
    float4 p = st[w][idx];
    float x0 = __expf(p.y - m0), x1 = __expf(p.z - m1);
    st[w][idx] = make_float4(p.x, x0, x1, 0.f);
    s0 += x0; s1 += x1;
  }
  for (int idx = CAP + lane; idx < tot; idx += 64) {
    int s = (idx < cnt) ? csr[beg + idx] : wid;
    float e0 = a_s[s * 2] + ad0, e1 = a_s[s * 2 + 1] + ad1;
    e0 = e0 > 0.f ? e0 : NEG * e0;
    e1 = e1 > 0.f ? e1 : NEG * e1;
    s0 += __expf(e0 - m0); s1 += __expf(e1 - m1);
  }
  s0 = wave_sum64(s0); s1 = wave_sum64(s1);

  int half = lane >> 5, fp = lane & 31;
  int hh2 = fp >> 4;                       // head owning this dword
  float invh = 1.f / (hh2 ? s1 : s0);
  float mh = hh2 ? m1 : m0;
  float adh = hh2 ? ad1 : ad0;

  const u32* hg2 = (const u32*)hg;  // 32 dwords per node row
  float acc0 = 0.f, acc1 = 0.f;
  for (int idx = half; idx < c1; idx += 2) {
    float4 p = st[w][idx];
    int s = __float_as_int(p.x);
    float a = hh2 ? p.z : p.y;
    u32 v = hg2[(size_t)s * 32 + fp];
    acc0 += bflo(v) * a;
    acc1 += bfhi(v) * a;
  }
  for (int idx = CAP + half; idx < tot; idx += 2) {
    int s = (idx < cnt) ? csr[beg + idx] : wid;
    float e = a_s[s * 2 + hh2] + adh;
    e = e > 0.f ? e : NEG * e;
    float a = __expf(e - mh);
    u32 v = hg2[(size_t)s * 32 + fp];
    acc0 += bflo(v) * a;
    acc1 += bfhi(v) * a;
  }
  acc0 += __shfl_xor(acc0, 32, 64);
  acc1 += __shfl_xor(acc1, 32, 64);

  // lanes 0..31 now hold complete sums; apply 1/sum then head mean (fp ^ 16)
  float v0 = acc0 * invh, v1 = acc1 * invh;
  v0 = 0.5f * (v0 + __shfl_xor(v0, 16, 64));
  v1 = 0.5f * (v1 + __shfl_xor(v1, 16, 64));
  int c0 = 2 * (fp & 15);
  v0 += bias[c0]; v1 += bias[c0 + 1];
  // log_softmax over 32 classes: values duplicated across 16-lane groups
  float mx = fmaxf(v0, v1);
#pragma unroll
  for (int m = 8; m >= 1; m >>= 1) mx = fmaxf(mx, __shfl_xor(mx, m, 64));
  float se = __expf(v0 - mx) + __expf(v1 - mx);
#pragma unroll
  for (int m = 8; m >= 1; m >>= 1) se += __shfl_xor(se, m, 64);
  float lse = mx + __logf(se);
  if (lane < 16) ((float2*)(out + (size_t)wid * 32))[fp] = make_float2(v0 - lse, v1 - lse);
}

// --------------------------------------------------------------------------
extern "C" void kernel_launch(void* const* d_in, const int* in_sizes, int n_in,
                              void* d_out, int out_size, void* d_ws, size_t ws_size,
                              hipStream_t stream) {
  (void)in_sizes; (void)n_in; (void)out_size; (void)ws_size;
  const float* x   = (const float*)d_in[0];
  const void*  ei  = d_in[1];
  const float* W1  = (const float*)d_in[2];
  const float* b1  = (const float*)d_in[3];
  const float* W2  = (const float*)d_in[4];
  const float* b2  = (const float*)d_in[5];
  const float* Wg1 = (const float*)d_in[6];
  const float* as1 = (const float*)d_in[7];
  const float* ad1 = (const float*)d_in[8];
  const float* bg1 = (const float*)d_in[9];
  const float* Wg2 = (const float*)d_in[10];
  const float* as2 = (const float*)d_in[11];
  const float* ad2 = (const float*)d_in[12];
  const float* bg2 = (const float*)d_in[13];
  float* out = (float*)d_out;

  char* w = (char*)d_ws;
  auto alloc = [&](size_t bytes) { char* p = w; w += (bytes + 255) & ~(size_t)255; return p; };
  u16* Hb     = (u16*)alloc((size_t)NN * 128 * 2);
  float* Hf   = (float*)alloc((size_t)NN * 128 * 4);
  float* dinv = (float*)alloc((size_t)NN * 4);
  float* asb  = (float*)alloc((size_t)NN * 2 * 4);
  float* adb  = (float*)alloc((size_t)NN * 2 * 4);
  int* deg    = (int*)alloc((size_t)NN * 4);
  int* rowp   = (int*)alloc((size_t)(NN + 1) * 4);
  int* cur    = (int*)alloc((size_t)NN * 4);
  int* csr    = (int*)alloc((size_t)EE * 4);
  int* bsums  = (int*)alloc(64 * 4);
  int* flag   = (int*)alloc(16);

  const int TB = 256;
  int gN = (NN + TB - 1) / TB;
  int gE = (EE + TB - 1) / TB;
  int gW = (NN + 3) / 4;          // wave per node
  int nScan = (NN + 1023) / 1024;

  k_detect<<<1, 256, 0, stream>>>(ei, flag);
  k_zero<<<gN, TB, 0, stream>>>(deg, cur);
  k_count<<<gE, TB, 0, stream>>>(ei, flag, deg);
  k_dinv<<<gN, TB, 0, stream>>>(deg, dinv);
  k_scan1<<<nScan, TB, 0, stream>>>(deg, rowp, bsums);
  k_scan2<<<1, 64, 0, stream>>>(bsums, rowp, nScan);
  k_scan3<<<gN, TB, 0, stream>>>(rowp, bsums);
  k_fill<<<gE, TB, 0, stream>>>(ei, flag, rowp, cur, csr);

  // GCN 1
  k_gemm<128, 64, 64><<<(NN + 63) / 64, TB, 0, stream>>>(x, W1, Hb, NN);
  k_gcn<<<gW, TB, 0, stream>>>(Hb, dinv, rowp, csr, b1, Hf);
  // GCN 2
  k_gemm<64, 64, 64><<<(NN + 63) / 64, TB, 0, stream>>>(Hf, W2, Hb, NN);
  k_gcn<<<gW, TB, 0, stream>>>(Hb, dinv, rowp, csr, b2, Hf);
  // GAT 1 (concat, relu)
  k_gemm<64, 128, 64><<<(NN + 63) / 64, TB, 0, stream>>>(Hf, Wg1, Hb, NN);
  k_att1<<<gW, TB, 0, stream>>>(Hb, as1, ad1, asb, adb);
  k_gat1<<<gW, TB, 0, stream>>>(Hb, asb, adb, rowp, csr, bg1, Hf);
  // GAT 2 (head mean) + log_softmax
  k_gemm<128, 64, 64><<<(NN + 63) / 64, TB, 0, stream>>>(Hf, Wg2, Hb, NN);
  k_att2<<<gW, TB, 0, stream>>>(Hb, as2, ad2, asb, adb);
  k_gat2<<<gW, TB, 0, stream>>>(Hb, asb, adb, rowp, csr, bg2, out);
}

// Round 5
// 350.839 us; speedup vs baseline: 1.1678x; 1.1678x over previous
//
#include <hip/hip_runtime.h>

#define NN 50000
#define EE 800000
#define NEG 0.2f
#define CAP 128   // per-wave LDS edge stash (deg ~Poisson(16), max ~45; fallback kept)

typedef long long i64;
typedef unsigned int u32;
typedef unsigned short u16;

static __device__ __forceinline__ float wave_max64(float v) {
#pragma unroll
  for (int m = 32; m >= 1; m >>= 1) v = fmaxf(v, __shfl_xor(v, m, 64));
  return v;
}
static __device__ __forceinline__ float wave_sum64(float v) {
#pragma unroll
  for (int m = 32; m >= 1; m >>= 1) v += __shfl_xor(v, m, 64);
  return v;
}

// bf16 helpers
static __device__ __forceinline__ u16 f2bf(float f) {
  u32 u = __float_as_uint(f);
  u += 0x7FFFu + ((u >> 16) & 1u);
  return (u16)(u >> 16);
}
// dword holding two bf16: lo = feature 2k, hi = feature 2k+1
static __device__ __forceinline__ float bflo(u32 v) { return __uint_as_float(v << 16); }
static __device__ __forceinline__ float bfhi(u32 v) { return __uint_as_float(v & 0xffff0000u); }

// ---- init: zero deg/cur + dtype probe (block 0) --------------------------
__global__ void k_init(const void* ei, int* flag, int* deg, int* cur) {
  int i = blockIdx.x * blockDim.x + threadIdx.x;
  if (i < NN) { deg[i] = 0; cur[i] = 0; }
  if (blockIdx.x == 0) {
    __shared__ int sbad[4];
    int t = threadIdx.x;
    const i64* p = (const i64*)ei;
    i64 v = p[t];
    int bad = (v < 0 || v >= NN) ? 1 : 0;
    unsigned long long b = __ballot(bad);
    if ((t & 63) == 0) sbad[t >> 6] = (b != 0ULL);
    __syncthreads();
    if (t == 0) *flag = !(sbad[0] | sbad[1] | sbad[2] | sbad[3]);
  }
}

static __device__ __forceinline__ int edge_at(const void* ei, int is64, int idx) {
  return is64 ? (int)((const i64*)ei)[idx] : ((const int*)ei)[idx];
}

__global__ void k_count(const void* ei, const int* flag, int* deg) {
  int e = blockIdx.x * blockDim.x + threadIdx.x;
  if (e >= EE) return;
  int is64 = *flag;
  atomicAdd(&deg[edge_at(ei, is64, EE + e)], 1);
}

// scan pass 1 + dinv fused
__global__ void k_scan1(const int* deg, int* rowp, int* bsums, float* dinv) {
  __shared__ int sh[256];
  int t = threadIdx.x;
  int base = blockIdx.x * 1024 + t * 4;
  int v[4]; int s = 0;
#pragma unroll
  for (int j = 0; j < 4; ++j) {
    int idx = base + j;
    int x = (idx < NN) ? deg[idx] : 0;
    v[j] = x; s += x;
    if (idx < NN) dinv[idx] = rsqrtf((float)(x + 1));
  }
  sh[t] = s; __syncthreads();
  for (int off = 1; off < 256; off <<= 1) {
    int x = (t >= off) ? sh[t - off] : 0;
    __syncthreads();
    sh[t] += x;
    __syncthreads();
  }
  if (t == 255) bsums[blockIdx.x] = sh[255];
  int run = sh[t] - s;
#pragma unroll
  for (int j = 0; j < 4; ++j) { int idx = base + j; if (idx < NN) rowp[idx] = run; run += v[j]; }
}

__global__ void k_scan2(int* bsums, int* rowp, int nb) {
  int lane = threadIdx.x & 63;
  int v = (lane < nb) ? bsums[lane] : 0;
  int x = v;
#pragma unroll
  for (int off = 1; off < 64; off <<= 1) {
    int y = __shfl_up(x, off, 64);
    if (lane >= off) x += y;
  }
  if (lane < nb) bsums[lane] = x - v;
  if (lane == 63) rowp[NN] = x;
}

__global__ void k_scan3(int* rowp, const int* bsums) {
  int i = blockIdx.x * blockDim.x + threadIdx.x;
  if (i < NN) rowp[i] += bsums[i >> 10];
}

__global__ void k_fill(const void* ei, const int* flag, const int* rowp, int* cur, int* csr) {
  int e = blockIdx.x * blockDim.x + threadIdx.x;
  if (e >= EE) return;
  int is64 = *flag;
  int s = edge_at(ei, is64, e);
  int d = edge_at(ei, is64, EE + e);
  int pos = rowp[d] + atomicAdd(&cur[d], 1);
  csr[pos] = s;
}

// ---- dense GEMM: Y(bf16)[n][OC] = X(f32)[n][K] @ W[K][OC] ----------------
template <int K, int OC, int ROWS>
__global__ void k_gemm(const float* __restrict__ X, const float* __restrict__ W,
                       u16* __restrict__ Y, int n) {
  __shared__ __align__(16) float Wl[K * OC];
  int t = threadIdx.x;
  for (int i = t; i < K * OC / 4; i += 256)
    ((float4*)Wl)[i] = ((const float4*)W)[i];
  __syncthreads();

  const int CP = OC / 2;
  const int RP = 256 / CP;
  int tx = t % CP, ty = t / CP;
  int blockRow = blockIdx.x * ROWS;
  const float2* Wl2 = (const float2*)Wl;

  for (int rp = 0; rp < ROWS; rp += RP * 2) {
    int r0 = blockRow + rp + ty * 2;
    if (r0 >= n) break;
    int r1 = r0 + 1;
    bool has1 = (r1 < n);
    const float4* x0q = (const float4*)(X + (size_t)r0 * K);
    const float4* x1q = (const float4*)(X + (size_t)(has1 ? r1 : r0) * K);
    float a00 = 0.f, a01 = 0.f, a10 = 0.f, a11 = 0.f;
#pragma unroll 4
    for (int k4 = 0; k4 < K / 4; ++k4) {
      float4 xa = x0q[k4];
      float4 xb = x1q[k4];
      const float* pa = &xa.x;
      const float* pb = &xb.x;
#pragma unroll
      for (int j = 0; j < 4; ++j) {
        float2 w2 = Wl2[(k4 * 4 + j) * CP + tx];
        a00 += pa[j] * w2.x; a01 += pa[j] * w2.y;
        a10 += pb[j] * w2.x; a11 += pb[j] * w2.y;
      }
    }
    ((ushort2*)(Y + (size_t)r0 * OC))[tx] = make_ushort2(f2bf(a00), f2bf(a01));
    if (has1) ((ushort2*)(Y + (size_t)r1 * OC))[tx] = make_ushort2(f2bf(a10), f2bf(a11));
  }
}

// ---- GEMM + fused attention-coefficient epilogue -------------------------
// G = lanes per head-group within a row (OC=128 -> 32, OC=64 -> 16)
template <int K, int OC, int ROWS, int G>
__global__ void k_gemm_att(const float* __restrict__ X, const float* __restrict__ W,
                           const float* __restrict__ aw_s, const float* __restrict__ aw_d,
                           u16* __restrict__ Y, float* __restrict__ a_sv,
                           float* __restrict__ a_dv, int n) {
  __shared__ __align__(16) float Wl[K * OC];
  int t = threadIdx.x;
  for (int i = t; i < K * OC / 4; i += 256)
    ((float4*)Wl)[i] = ((const float4*)W)[i];
  __syncthreads();

  const int CP = OC / 2;
  const int RP = 256 / CP;
  int tx = t % CP, ty = t / CP;
  int blockRow = blockIdx.x * ROWS;
  const float2* Wl2 = (const float2*)Wl;
  float2 aws2 = ((const float2*)aw_s)[tx];
  float2 awd2 = ((const float2*)aw_d)[tx];
  int hh = (tx / G) & 1;

  for (int rp = 0; rp < ROWS; rp += RP * 2) {
    int r0 = blockRow + rp + ty * 2;
    if (r0 >= n) break;
    int r1 = r0 + 1;
    bool has1 = (r1 < n);
    const float4* x0q = (const float4*)(X + (size_t)r0 * K);
    const float4* x1q = (const float4*)(X + (size_t)(has1 ? r1 : r0) * K);
    float a00 = 0.f, a01 = 0.f, a10 = 0.f, a11 = 0.f;
#pragma unroll 4
    for (int k4 = 0; k4 < K / 4; ++k4) {
      float4 xa = x0q[k4];
      float4 xb = x1q[k4];
      const float* pa = &xa.x;
      const float* pb = &xb.x;
#pragma unroll
      for (int j = 0; j < 4; ++j) {
        float2 w2 = Wl2[(k4 * 4 + j) * CP + tx];
        a00 += pa[j] * w2.x; a01 += pa[j] * w2.y;
        a10 += pb[j] * w2.x; a11 += pb[j] * w2.y;
      }
    }
    ((ushort2*)(Y + (size_t)r0 * OC))[tx] = make_ushort2(f2bf(a00), f2bf(a01));
    if (has1) ((ushort2*)(Y + (size_t)r1 * OC))[tx] = make_ushort2(f2bf(a10), f2bf(a11));

    // attention coefficients from fp32 accumulators (pre-rounding)
    float sp0 = a00 * aws2.x + a01 * aws2.y;
    float dp0 = a00 * awd2.x + a01 * awd2.y;
    float sp1 = a10 * aws2.x + a11 * aws2.y;
    float dp1 = a10 * awd2.x + a11 * awd2.y;
#pragma unroll
    for (int mm = G / 2; mm >= 1; mm >>= 1) {
      sp0 += __shfl_xor(sp0, mm, 64); dp0 += __shfl_xor(dp0, mm, 64);
      sp1 += __shfl_xor(sp1, mm, 64); dp1 += __shfl_xor(dp1, mm, 64);
    }
    if ((tx & (G - 1)) == 0) {
      a_sv[r0 * 2 + hh] = sp0; a_dv[r0 * 2 + hh] = dp0;
      if (has1) { a_sv[r1 * 2 + hh] = sp1; a_dv[r1 * 2 + hh] = dp1; }
    }
  }
}

// ---- GCN aggregation: wave/node; halves alternate edges; unroll 4 --------
__global__ void k_gcn(const u16* __restrict__ g, const float* __restrict__ dinv,
                      const int* __restrict__ rowp, const int* __restrict__ csr,
                      const float* __restrict__ bias, float* __restrict__ out) {
  __shared__ int   s_src[4][CAP];
  __shared__ float s_wt[4][CAP];
  int wid = (blockIdx.x * blockDim.x + threadIdx.x) >> 6;
  int w = (threadIdx.x >> 6) & 3;
  int lane = threadIdx.x & 63;
  if (wid >= NN) return;
  float di = dinv[wid];
  int beg = rowp[wid], cnt = rowp[wid + 1] - beg;
  int c1 = min(cnt, CAP);

  for (int idx = lane; idx < c1; idx += 64) {
    int s = csr[beg + idx];
    s_src[w][idx] = s; s_wt[w][idx] = dinv[s];
  }

  int half = lane >> 5, fp = lane & 31;
  const u32* g2 = (const u32*)g;   // 32 dwords per node row
  float acc0 = 0.f, acc1 = 0.f;
  int idx = half;
  for (; idx + 6 < c1; idx += 8) {
    int sA = s_src[w][idx],     sB = s_src[w][idx + 2];
    int sC = s_src[w][idx + 4], sD = s_src[w][idx + 6];
    float wA = s_wt[w][idx],     wB = s_wt[w][idx + 2];
    float wC = s_wt[w][idx + 4], wD = s_wt[w][idx + 6];
    u32 vA = g2[(size_t)sA * 32 + fp], vB = g2[(size_t)sB * 32 + fp];
    u32 vC = g2[(size_t)sC * 32 + fp], vD = g2[(size_t)sD * 32 + fp];
    acc0 += bflo(vA) * wA + bflo(vB) * wB + bflo(vC) * wC + bflo(vD) * wD;
    acc1 += bfhi(vA) * wA + bfhi(vB) * wB + bfhi(vC) * wC + bfhi(vD) * wD;
  }
  for (; idx < c1; idx += 2) {
    int s = s_src[w][idx]; float ws = s_wt[w][idx];
    u32 v = g2[(size_t)s * 32 + fp];
    acc0 += bflo(v) * ws; acc1 += bfhi(v) * ws;
  }
  for (idx = CAP + half; idx < cnt; idx += 2) {  // essentially never
    int s = csr[beg + idx];
    float ws = dinv[s];
    u32 v = g2[(size_t)s * 32 + fp];
    acc0 += bflo(v) * ws; acc1 += bfhi(v) * ws;
  }
  if (half == 0) {  // self loop
    u32 v = g2[(size_t)wid * 32 + fp];
    acc0 += bflo(v) * di; acc1 += bfhi(v) * di;
  }
  acc0 += __shfl_xor(acc0, 32, 64);
  acc1 += __shfl_xor(acc1, 32, 64);
  if (half == 0) {
    float v0 = fmaxf(acc0 * di + bias[2 * fp], 0.f);
    float v1 = fmaxf(acc1 * di + bias[2 * fp + 1], 0.f);
    ((float2*)(out + (size_t)wid * 64))[fp] = make_float2(v0, v1);
  }
}

// ---- GAT layer 1: wave per node, both heads; lane = dword 0..63 ----------
__global__ void k_gat1(const u16* __restrict__ hg, const float* __restrict__ a_s,
                       const float* __restrict__ a_d, const int* __restrict__ rowp,
                       const int* __restrict__ csr, const float* __restrict__ bias,
                       float* __restrict__ out) {
  __shared__ int   s_src[4][CAP];
  __shared__ float s_x0[4][CAP];
  __shared__ float s_x1[4][CAP];
  int wid = (blockIdx.x * blockDim.x + threadIdx.x) >> 6;
  int w = (threadIdx.x >> 6) & 3;
  int lane = threadIdx.x & 63;
  if (wid >= NN) return;
  int beg = rowp[wid], cnt = rowp[wid + 1] - beg;
  int tot = cnt + 1;
  int c1 = min(tot, CAP);
  float ad0 = a_d[wid * 2], ad1 = a_d[wid * 2 + 1];
  float m0, m1, inv0, inv1;

  if (tot <= 64) {  // fast path: one edge per lane, straight-line softmax
    bool act = lane < tot;
    int s = (lane < cnt) ? csr[beg + lane] : wid;
    float e0 = -1e30f, e1 = -1e30f;
    if (act) {
      float2 av = ((const float2*)a_s)[s];
      e0 = av.x + ad0; e0 = e0 > 0.f ? e0 : NEG * e0;
      e1 = av.y + ad1; e1 = e1 > 0.f ? e1 : NEG * e1;
    }
    m0 = wave_max64(e0); m1 = wave_max64(e1);
    float x0 = act ? __expf(e0 - m0) : 0.f;
    float x1 = act ? __expf(e1 - m1) : 0.f;
    inv0 = 1.f / wave_sum64(x0); inv1 = 1.f / wave_sum64(x1);
    if (act) { s_src[w][lane] = s; s_x0[w][lane] = x0; s_x1[w][lane] = x1; }
  } else {  // generic fallback
    float mm0 = -1e30f, mm1 = -1e30f;
    for (int idx = lane; idx < tot; idx += 64) {
      int s = (idx < cnt) ? csr[beg + idx] : wid;
      float2 av = ((const float2*)a_s)[s];
      float e0 = av.x + ad0; e0 = e0 > 0.f ? e0 : NEG * e0;
      float e1 = av.y + ad1; e1 = e1 > 0.f ? e1 : NEG * e1;
      if (idx < CAP) { s_src[w][idx] = s; s_x0[w][idx] = e0; s_x1[w][idx] = e1; }
      mm0 = fmaxf(mm0, e0); mm1 = fmaxf(mm1, e1);
    }
    m0 = wave_max64(mm0); m1 = wave_max64(mm1);
    float ss0 = 0.f, ss1 = 0.f;
    for (int idx = lane; idx < c1; idx += 64) {
      float x0 = __expf(s_x0[w][idx] - m0), x1 = __expf(s_x1[w][idx] - m1);
      s_x0[w][idx] = x0; s_x1[w][idx] = x1;
      ss0 += x0; ss1 += x1;
    }
    for (int idx = CAP + lane; idx < tot; idx += 64) {
      int s = (idx < cnt) ? csr[beg + idx] : wid;
      float2 av = ((const float2*)a_s)[s];
      float e0 = av.x + ad0; e0 = e0 > 0.f ? e0 : NEG * e0;
      float e1 = av.y + ad1; e1 = e1 > 0.f ? e1 : NEG * e1;
      ss0 += __expf(e0 - m0); ss1 += __expf(e1 - m1);
    }
    inv0 = 1.f / wave_sum64(ss0); inv1 = 1.f / wave_sum64(ss1);
  }

  bool hi = (lane >= 32);
  float invh = hi ? inv1 : inv0, mh = hi ? m1 : m0, adh = hi ? ad1 : ad0;
  const u32* hg2 = (const u32*)hg;  // 64 dwords per node row
  float acc0 = 0.f, acc1 = 0.f;
  int idx = 0;
  for (; idx + 3 < c1; idx += 4) {
    int sA = s_src[w][idx],     sB = s_src[w][idx + 1];
    int sC = s_src[w][idx + 2], sD = s_src[w][idx + 3];
    float aA = hi ? s_x1[w][idx]     : s_x0[w][idx];
    float aB = hi ? s_x1[w][idx + 1] : s_x0[w][idx + 1];
    float aC = hi ? s_x1[w][idx + 2] : s_x0[w][idx + 2];
    float aD = hi ? s_x1[w][idx + 3] : s_x0[w][idx + 3];
    u32 vA = hg2[(size_t)sA * 64 + lane], vB = hg2[(size_t)sB * 64 + lane];
    u32 vC = hg2[(size_t)sC * 64 + lane], vD = hg2[(size_t)sD * 64 + lane];
    acc0 += bflo(vA) * aA + bflo(vB) * aB + bflo(vC) * aC + bflo(vD) * aD;
    acc1 += bfhi(vA) * aA + bfhi(vB) * aB + bfhi(vC) * aC + bfhi(vD) * aD;
  }
  for (; idx < c1; ++idx) {
    int s = s_src[w][idx];
    float a = hi ? s_x1[w][idx] : s_x0[w][idx];
    u32 v = hg2[(size_t)s * 64 + lane];
    acc0 += bflo(v) * a; acc1 += bfhi(v) * a;
  }
  for (; idx < tot; ++idx) {  // beyond CAP
    int s = (idx < cnt) ? csr[beg + idx] : wid;
    float e = (hi ? a_s[s * 2 + 1] : a_s[s * 2]) + adh;
    e = e > 0.f ? e : NEG * e;
    float a = __expf(e - mh);
    u32 v = hg2[(size_t)s * 64 + lane];
    acc0 += bflo(v) * a; acc1 += bfhi(v) * a;
  }
  float v0 = fmaxf(acc0 * invh + bias[2 * lane], 0.f);
  float v1 = fmaxf(acc1 * invh + bias[2 * lane + 1], 0.f);
  ((float2*)(out + (size_t)wid * 128))[lane] = make_float2(v0, v1);
}

// ---- GAT layer 2 (H=2,C=32, head-mean) + log_softmax ---------------------
__global__ void k_gat2(const u16* __restrict__ hg, const float* __restrict__ a_s,
                       const float* __restrict__ a_d, const int* __restrict__ rowp,
                       const int* __restrict__ csr, const float* __restrict__ bias,
                       float* __restrict__ out) {
  __shared__ int   s_src[4][CAP];
  __shared__ float s_x0[4][CAP];
  __shared__ float s_x1[4][CAP];
  int wid = (blockIdx.x * blockDim.x + threadIdx.x) >> 6;
  int w = (threadIdx.x >> 6) & 3;
  int lane = threadIdx.x & 63;
  if (wid >= NN) return;
  int beg = rowp[wid], cnt = rowp[wid + 1] - beg;
  int tot = cnt + 1;
  int c1 = min(tot, CAP);
  float ad0 = a_d[wid * 2], ad1 = a_d[wid * 2 + 1];
  float m0, m1, inv0, inv1;

  if (tot <= 64) {
    bool act = lane < tot;
    int s = (lane < cnt) ? csr[beg + lane] : wid;
    float e0 = -1e30f, e1 = -1e30f;
    if (act) {
      float2 av = ((const float2*)a_s)[s];
      e0 = av.x + ad0; e0 = e0 > 0.f ? e0 : NEG * e0;
      e1 = av.y + ad1; e1 = e1 > 0.f ? e1 : NEG * e1;
    }
    m0 = wave_max64(e0); m1 = wave_max64(e1);
    float x0 = act ? __expf(e0 - m0) : 0.f;
    float x1 = act ? __expf(e1 - m1) : 0.f;
    inv0 = 1.f / wave_sum64(x0); inv1 = 1.f / wave_sum64(x1);
    if (act) { s_src[w][lane] = s; s_x0[w][lane] = x0; s_x1[w][lane] = x1; }
  } else {
    float mm0 = -1e30f, mm1 = -1e30f;
    for (int idx = lane; idx < tot; idx += 64) {
      int s = (idx < cnt) ? csr[beg + idx] : wid;
      float2 av = ((const float2*)a_s)[s];
      float e0 = av.x + ad0; e0 = e0 > 0.f ? e0 : NEG * e0;
      float e1 = av.y + ad1; e1 = e1 > 0.f ? e1 : NEG * e1;
      if (idx < CAP) { s_src[w][idx] = s; s_x0[w][idx] = e0; s_x1[w][idx] = e1; }
      mm0 = fmaxf(mm0, e0); mm1 = fmaxf(mm1, e1);
    }
    m0 = wave_max64(mm0); m1 = wave_max64(mm1);
    float ss0 = 0.f, ss1 = 0.f;
    for (int idx = lane; idx < c1; idx += 64) {
      float x0 = __expf(s_x0[w][idx] - m0), x1 = __expf(s_x1[w][idx] - m1);
      s_x0[w][idx] = x0; s_x1[w][idx] = x1;
      ss0 += x0; ss1 += x1;
    }
    for (int idx = CAP + lane; idx < tot; idx += 64) {
      int s = (idx < cnt) ? csr[beg + idx] : wid;
      float2 av = ((const float2*)a_s)[s];
      float e0 = av.x + ad0; e0 = e0 > 0.f ? e0 : NEG * e0;
      float e1 = av.y + ad1; e1 = e1 > 0.f ? e1 : NEG * e1;
      ss0 += __expf(e0 - m0); ss1 += __expf(e1 - m1);
    }
    inv0 = 1.f / wave_sum64(ss0); inv1 = 1.f / wave_sum64(ss1);
  }

  int half = lane >> 5, fp = lane & 31;
  int hh2 = fp >> 4;                       // head owning this dword
  float invh = hh2 ? inv1 : inv0;
  float mh = hh2 ? m1 : m0;
  float adh = hh2 ? ad1 : ad0;

  const u32* hg2 = (const u32*)hg;  // 32 dwords per node row
  float acc0 = 0.f, acc1 = 0.f;
  int idx = half;
  for (; idx + 6 < c1; idx += 8) {
    int sA = s_src[w][idx],     sB = s_src[w][idx + 2];
    int sC = s_src[w][idx + 4], sD = s_src[w][idx + 6];
    float aA = hh2 ? s_x1[w][idx]     : s_x0[w][idx];
    float aB = hh2 ? s_x1[w][idx + 2] : s_x0[w][idx + 2];
    float aC = hh2 ? s_x1[w][idx + 4] : s_x0[w][idx + 4];
    float aD = hh2 ? s_x1[w][idx + 6] : s_x0[w][idx + 6];
    u32 vA = hg2[(size_t)sA * 32 + fp], vB = hg2[(size_t)sB * 32 + fp];
    u32 vC = hg2[(size_t)sC * 32 + fp], vD = hg2[(size_t)sD * 32 + fp];
    acc0 += bflo(vA) * aA + bflo(vB) * aB + bflo(vC) * aC + bflo(vD) * aD;
    acc1 += bfhi(vA) * aA + bfhi(vB) * aB + bfhi(vC) * aC + bfhi(vD) * aD;
  }
  for (; idx < c1; idx += 2) {
    int s = s_src[w][idx];
    float a = hh2 ? s_x1[w][idx] : s_x0[w][idx];
    u32 v = hg2[(size_t)s * 32 + fp];
    acc0 += bflo(v) * a; acc1 += bfhi(v) * a;
  }
  for (idx = CAP + half; idx < tot; idx += 2) {
    int s = (idx < cnt) ? csr[beg + idx] : wid;
    float e = a_s[s * 2 + hh2] + adh;
    e = e > 0.f ? e : NEG * e;
    float a = __expf(e - mh);
    u32 v = hg2[(size_t)s * 32 + fp];
    acc0 += bflo(v) * a; acc1 += bfhi(v) * a;
  }
  acc0 += __shfl_xor(acc0, 32, 64);
  acc1 += __shfl_xor(acc1, 32, 64);

  float v0 = acc0 * invh, v1 = acc1 * invh;
  v0 = 0.5f * (v0 + __shfl_xor(v0, 16, 64));   // head mean
  v1 = 0.5f * (v1 + __shfl_xor(v1, 16, 64));
  int c0 = 2 * (fp & 15);
  v0 += bias[c0]; v1 += bias[c0 + 1];
  float mx = fmaxf(v0, v1);
#pragma unroll
  for (int m = 8; m >= 1; m >>= 1) mx = fmaxf(mx, __shfl_xor(mx, m, 64));
  float se = __expf(v0 - mx) + __expf(v1 - mx);
#pragma unroll
  for (int m = 8; m >= 1; m >>= 1) se += __shfl_xor(se, m, 64);
  float lse = mx + __logf(se);
  if (lane < 16) ((float2*)(out + (size_t)wid * 32))[fp] = make_float2(v0 - lse, v1 - lse);
}

// --------------------------------------------------------------------------
extern "C" void kernel_launch(void* const* d_in, const int* in_sizes, int n_in,
                              void* d_out, int out_size, void* d_ws, size_t ws_size,
                              hipStream_t stream) {
  (void)in_sizes; (void)n_in; (void)out_size; (void)ws_size;
  const float* x   = (const float*)d_in[0];
  const void*  ei  = d_in[1];
  const float* W1  = (const float*)d_in[2];
  const float* b1  = (const float*)d_in[3];
  const float* W2  = (const float*)d_in[4];
  const float* b2  = (const float*)d_in[5];
  const float* Wg1 = (const float*)d_in[6];
  const float* as1 = (const float*)d_in[7];
  const float* ad1 = (const float*)d_in[8];
  const float* bg1 = (const float*)d_in[9];
  const float* Wg2 = (const float*)d_in[10];
  const float* as2 = (const float*)d_in[11];
  const float* ad2 = (const float*)d_in[12];
  const float* bg2 = (const float*)d_in[13];
  float* out = (float*)d_out;

  char* w = (char*)d_ws;
  auto alloc = [&](size_t bytes) { char* p = w; w += (bytes + 255) & ~(size_t)255; return p; };
  u16* Hb     = (u16*)alloc((size_t)NN * 128 * 2);
  float* Hf   = (float*)alloc((size_t)NN * 128 * 4);
  float* dinv = (float*)alloc((size_t)NN * 4);
  float* asb  = (float*)alloc((size_t)NN * 2 * 4);
  float* adb  = (float*)alloc((size_t)NN * 2 * 4);
  int* deg    = (int*)alloc((size_t)NN * 4);
  int* rowp   = (int*)alloc((size_t)(NN + 1) * 4);
  int* cur    = (int*)alloc((size_t)NN * 4);
  int* csr    = (int*)alloc((size_t)EE * 4);
  int* bsums  = (int*)alloc(64 * 4);
  int* flag   = (int*)alloc(16);

  const int TB = 256;
  int gN = (NN + TB - 1) / TB;
  int gE = (EE + TB - 1) / TB;
  int gW = (NN + 3) / 4;          // wave per node
  int nScan = (NN + 1023) / 1024;
  int gG = (NN + 63) / 64;        // gemm blocks

  k_init<<<gN, TB, 0, stream>>>(ei, flag, deg, cur);
  k_count<<<gE, TB, 0, stream>>>(ei, flag, deg);
  k_scan1<<<nScan, TB, 0, stream>>>(deg, rowp, bsums, dinv);
  k_scan2<<<1, 64, 0, stream>>>(bsums, rowp, nScan);
  k_scan3<<<gN, TB, 0, stream>>>(rowp, bsums);
  k_fill<<<gE, TB, 0, stream>>>(ei, flag, rowp, cur, csr);

  // GCN 1
  k_gemm<128, 64, 64><<<gG, TB, 0, stream>>>(x, W1, Hb, NN);
  k_gcn<<<gW, TB, 0, stream>>>(Hb, dinv, rowp, csr, b1, Hf);
  // GCN 2
  k_gemm<64, 64, 64><<<gG, TB, 0, stream>>>(Hf, W2, Hb, NN);
  k_gcn<<<gW, TB, 0, stream>>>(Hb, dinv, rowp, csr, b2, Hf);
  // GAT 1 (concat, relu): gemm + fused att coefficients
  k_gemm_att<64, 128, 64, 32><<<gG, TB, 0, stream>>>(Hf, Wg1, as1, ad1, Hb, asb, adb, NN);
  k_gat1<<<gW, TB, 0, stream>>>(Hb, asb, adb, rowp, csr, bg1, Hf);
  // GAT 2 (head mean) + log_softmax
  k_gemm_att<128, 64, 64, 16><<<gG, TB, 0, stream>>>(Hf, Wg2, as2, ad2, Hb, asb, adb, NN);
  k_gat2<<<gW, TB, 0, stream>>>(Hb, asb, adb, rowp, csr, bg2, out);
}